// Round 6
// baseline (694.368 us; speedup 1.0000x reference)
//
#include <hip/hip_runtime.h>

// FP16 bit-pulse -> FP32 bit-pulse converter, v3.
// One task per input uint4 (4 "bit" floats = 4 consecutive input bits).
// Element e = h>>2, nibble index q = h&3. The 4 lanes sharing an element
// OR-combine their 4-bit contributions with 2 shfl_xor ops; every lane then
// computes the element's 32-bit output pattern with exact integer logic and
// stores output parts q and q+4 (two coalesced float4 stores covering the
// element's 8 output float4s across its 4-lane group).
//   E==0  -> signed zero (covers reference's zero AND subnormal-flush paths)
//   E==31 -> exp=0xFF, mantissa = M (inf has M==0, NaN keeps M)
//   else  -> exp=E+112, mantissa = M << 13
// All memory ops nontemporal: pure one-touch streaming, keep it out of L3.

typedef unsigned int uint4v __attribute__((ext_vector_type(4)));
typedef float float4v __attribute__((ext_vector_type(4)));

__global__ __launch_bounds__(256) void fp16_to_fp32_bits_kernel(
    const uint4v* __restrict__ in, float4v* __restrict__ out, int n_tasks) {
    int tid = blockIdx.x * blockDim.x + threadIdx.x;
    int stride = gridDim.x * blockDim.x;
    for (int h = tid; h < n_tasks; h += stride) {
        uint4v u = __builtin_nontemporal_load(in + h);
        unsigned q = (unsigned)h & 3u;
        // 4 input bit-floats -> 4-bit nibble (float 0.0/1.0 -> bit 0/1)
        unsigned nib = (u.x ? 1u : 0u) | (u.y ? 2u : 0u) |
                       (u.z ? 4u : 0u) | (u.w ? 8u : 0u);
        unsigned local = nib << (4u * q);
        // OR-combine across the 4-lane element group (xor masks 1,2 stay in-group)
        local |= __shfl_xor((int)local, 1);
        local |= __shfl_xor((int)local, 2);
        // local: bit j = x[..., j] (j=0 sign, 1..5 exp MSB->LSB, 6..15 mantissa)

        unsigned E = __brev(local >> 1) >> 27;  // numeric 5-bit exponent
        unsigned exp8 = (E == 31u) ? 255u : ((E == 0u) ? 0u : E + 112u);
        unsigned mmask = (E == 0u) ? 0u : 0x3FFu;

        // 32-bit output pattern: bit k = output float index k
        unsigned obits = (local & 1u)                      // sign
                       | ((__brev(exp8) >> 24) << 1)       // exp MSB-first at o[1..8]
                       | (((local >> 6) & mmask) << 9);    // mantissa at o[9..18]

        unsigned base = (((unsigned)h >> 2) << 3) + q;     // e*8 + q
        unsigned nA = (obits >> (4u * q)) & 0xFu;          // part q
        unsigned nB = (obits >> (4u * q + 16u)) & 0xFu;    // part q+4
        float4v a = {(float)(nA & 1u), (float)((nA >> 1) & 1u),
                     (float)((nA >> 2) & 1u), (float)((nA >> 3) & 1u)};
        float4v b = {(float)(nB & 1u), (float)((nB >> 1) & 1u),
                     (float)((nB >> 2) & 1u), (float)((nB >> 3) & 1u)};
        __builtin_nontemporal_store(a, out + base);
        __builtin_nontemporal_store(b, out + base + 4);
    }
}

extern "C" void kernel_launch(void* const* d_in, const int* in_sizes, int n_in,
                              void* d_out, int out_size, void* d_ws, size_t ws_size,
                              hipStream_t stream) {
    const uint4v* in = (const uint4v*)d_in[0];
    float4v* out = (float4v*)d_out;
    int n_tasks = in_sizes[0] / 4;  // one task per input uint4 (4 bits)
    int block = 256;
    int maxBlocks = 2048;  // 256 CUs x 8 blocks/CU; grid-stride the rest
    int blocks = (n_tasks + block - 1) / block;
    if (blocks > maxBlocks) blocks = maxBlocks;
    fp16_to_fp32_bits_kernel<<<blocks, block, 0, stream>>>(in, out, n_tasks);
}

// Round 7
// 676.577 us; speedup vs baseline: 1.0263x; 1.0263x over previous
//
#include <hip/hip_runtime.h>

// FP16 bit-pulse -> FP32 bit-pulse converter, lane-interleaved (round-3 best).
//
// Task g (one per output float4): element e = g>>3, part p = g&7.
// Input float2 at flat index g belongs to the SAME element (e = g>>3,
// bit-pair q = g&7) -- so one flat index drives both the coalesced 8B load
// and the coalesced 16B store.
//
// The 8 lanes sharing an element exchange their 2-bit contributions with
// 3 shfl_xor ops; every lane then computes the element's full 32-bit output
// pattern with exact integer logic:
//   E==0  -> signed zero (covers reference's zero AND subnormal-flush paths)
//   E==31 -> exp=0xFF, mantissa = M (inf has M==0, NaN keeps M)
//   else  -> exp=E+112, mantissa = M << 13
//
// Measured: 676 us total (abs ~146 us kernel, ~5.3 TB/s mixed-stream).
// v3 (uint4 + nontemporal) regressed to 694 us -- nt buys nothing here
// because the harness's 2.1 GB poison fills flush L2/L3 anyway.
__global__ __launch_bounds__(256) void fp16_to_fp32_bits_kernel(
    const uint2* __restrict__ in, float4* __restrict__ out, int n_tasks) {
    int tid = blockIdx.x * blockDim.x + threadIdx.x;
    int stride = gridDim.x * blockDim.x;
    for (int g = tid; g < n_tasks; g += stride) {
        uint2 u = in[g];                 // two input "bit" floats (0.0f or 1.0f)
        unsigned q = (unsigned)g & 7u;   // bit-pair index == output part index
        unsigned local = ((u.x ? 1u : 0u) | (u.y ? 2u : 0u)) << (2u * q);
        // OR-combine across the 8-lane element group (xor masks 1,2,4 stay in-group)
        local |= __shfl_xor((int)local, 1);
        local |= __shfl_xor((int)local, 2);
        local |= __shfl_xor((int)local, 4);
        // local: bit j = x[..., j] of this element (j=0 sign, 1..5 exp MSB->LSB, 6..15 mant)

        // 5-bit exponent value: numeric bit4 = x1 ... bit0 = x5 (bit-reverse of local>>1)
        unsigned E = __brev(local >> 1) >> 27;
        unsigned exp8 = (E == 31u) ? 255u : ((E == 0u) ? 0u : E + 112u);
        unsigned mmask = (E == 0u) ? 0u : 0x3FFu;

        // 32-bit output pattern: bit k = output float index k
        unsigned obits = (local & 1u)                      // sign
                       | ((__brev(exp8) >> 24) << 1)       // exp bits, MSB first at o[1..8]
                       | (((local >> 6) & mmask) << 9);    // mantissa at o[9..18]

        unsigned nib = (obits >> (4u * q)) & 0xFu;
        out[g] = make_float4((float)(nib & 1u), (float)((nib >> 1) & 1u),
                             (float)((nib >> 2) & 1u), (float)((nib >> 3) & 1u));
    }
}

extern "C" void kernel_launch(void* const* d_in, const int* in_sizes, int n_in,
                              void* d_out, int out_size, void* d_ws, size_t ws_size,
                              hipStream_t stream) {
    const uint2* in = (const uint2*)d_in[0];
    float4* out = (float4*)d_out;
    int n_tasks = in_sizes[0] / 2;  // one task per input float2 / output float4
    int block = 256;
    int maxBlocks = 2048;  // 256 CUs x 8 blocks/CU; grid-stride the rest
    int blocks = (n_tasks + block - 1) / block;
    if (blocks > maxBlocks) blocks = maxBlocks;
    fp16_to_fp32_bits_kernel<<<blocks, block, 0, stream>>>(in, out, n_tasks);
}